// Round 2
// baseline (874.410 us; speedup 1.0000x reference)
//
#include <hip/hip_runtime.h>
#include <hip/hip_fp16.h>

#define N_NODES 25000
#define N_EDGES 400000
#define EPS_F 1e-5f

__device__ __forceinline__ float silu_f(float x) {
    return x / (1.0f + __expf(-x));
}

// ---------------------------------------------------------------------------
// K1: per-node linear transforms (node-per-lane; weight reads are uniform ->
// scalar loads; node row lives in VGPRs with static indexing only).
// XS/SC row layout (stride 192 f32): [0..63]=s, [64 + v*4 + c]=v (c<3, pad).
// ---------------------------------------------------------------------------
__global__ __launch_bounds__(256) void k_node_pre(
    const float* __restrict__ nh,
    const float* __restrict__ W1_0, const float* __restrict__ W1_1,
    const float* __restrict__ Wsc0, const float* __restrict__ Wsc1,
    float* __restrict__ XS, float* __restrict__ SC)
{
    int n = blockIdx.x * 256 + threadIdx.x;
    if (n >= N_NODES) return;
    const float* row = nh + (size_t)n * 160;
    float* xsrow = XS + (size_t)n * 192;
    float* scrow = SC + (size_t)n * 192;

    // ---- scalar channels ----
    float si[64];
#pragma unroll
    for (int m = 0; m < 16; ++m) {
        float4 t = *(const float4*)(row + m * 4);
        si[4*m+0] = t.x; si[4*m+1] = t.y; si[4*m+2] = t.z; si[4*m+3] = t.w;
    }
#pragma unroll 1
    for (int jg = 0; jg < 16; ++jg) {
        float a0=0,a1=0,a2=0,a3=0,b0=0,b1=0,b2=0,b3=0;
#pragma unroll
        for (int k = 0; k < 64; ++k) {
            float wa[4]; *(float4*)wa = *(const float4*)(W1_0 + k*64 + jg*4);
            float wb[4]; *(float4*)wb = *(const float4*)(Wsc0 + k*64 + jg*4);
            float s = si[k];
            a0 += s*wa[0]; a1 += s*wa[1]; a2 += s*wa[2]; a3 += s*wa[3];
            b0 += s*wb[0]; b1 += s*wb[1]; b2 += s*wb[2]; b3 += s*wb[3];
        }
        const float sc8 = 0.125f; // 1/sqrt(64)
        *(float4*)(xsrow + jg*4) = make_float4(a0*sc8, a1*sc8, a2*sc8, a3*sc8);
        *(float4*)(scrow + jg*4) = make_float4(b0*sc8, b1*sc8, b2*sc8, b3*sc8);
    }

    // ---- vector channels: v_in[u][c] = row[64 + u*3 + c] ----
    float vi[96];
#pragma unroll
    for (int m = 0; m < 24; ++m) {
        float4 t = *(const float4*)(row + 64 + m * 4);
        vi[4*m+0] = t.x; vi[4*m+1] = t.y; vi[4*m+2] = t.z; vi[4*m+3] = t.w;
    }
    const float is32 = 0.17677669529663687f; // 1/sqrt(32)
#pragma unroll 1
    for (int vg = 0; vg < 8; ++vg) {
        float a[4][3], b[4][3];
#pragma unroll
        for (int m = 0; m < 4; ++m) { a[m][0]=a[m][1]=a[m][2]=0.f; b[m][0]=b[m][1]=b[m][2]=0.f; }
#pragma unroll
        for (int u = 0; u < 32; ++u) {
            float wa[4]; *(float4*)wa = *(const float4*)(W1_1 + u*32 + vg*4);
            float wb[4]; *(float4*)wb = *(const float4*)(Wsc1 + u*32 + vg*4);
            float vx = vi[u*3+0], vy = vi[u*3+1], vz = vi[u*3+2];
#pragma unroll
            for (int m = 0; m < 4; ++m) {
                a[m][0] += vx*wa[m]; a[m][1] += vy*wa[m]; a[m][2] += vz*wa[m];
                b[m][0] += vx*wb[m]; b[m][1] += vy*wb[m]; b[m][2] += vz*wb[m];
            }
        }
#pragma unroll
        for (int m = 0; m < 4; ++m) {
            int v = vg*4 + m;
            *(float4*)(xsrow + 64 + v*4) = make_float4(a[m][0]*is32, a[m][1]*is32, a[m][2]*is32, 0.f);
            *(float4*)(scrow + 64 + v*4) = make_float4(b[m][0]*is32, b[m][1]*is32, b[m][2]*is32, 0.f);
        }
    }
}

// ---------------------------------------------------------------------------
// K2: per-src edge lists. Only int atomics (400k). Cap 64 (Poisson(16) max
// over 25k nodes ~34 with overwhelming probability).
// ---------------------------------------------------------------------------
__global__ __launch_bounds__(256) void k_build_lists(
    const int* __restrict__ ei, int* __restrict__ CNT, int* __restrict__ LIST)
{
    int e = blockIdx.x * 256 + threadIdx.x;
    if (e >= N_EDGES) return;
    int src = ei[e];                       // row 0 = edge_src
    int pos = atomicAdd(&CNT[src], 1);
    if (pos < 64) LIST[src*64 + pos] = e;
}

// ---------------------------------------------------------------------------
// K3: FUSED edge MLP, all 3 layers (edge-per-lane). Uniform weight addresses
// -> scalar/broadcast loads. h1/h2 in registers with static indexing only.
// Output w -> fp16 row-major (224/edge) so K4's per-edge reads are
// lane-coalesced. (Fused to avoid a 51 MB H2 buffer: ws must stay <256 MB.)
// ---------------------------------------------------------------------------
__global__ __launch_bounds__(256) void k_edge_mlp(
    const float* __restrict__ eat,
    const float* __restrict__ Wfc1, const float* __restrict__ Wfc2,
    const float* __restrict__ Wfc3,
    __half* __restrict__ WE)
{
    int e = blockIdx.x * 256 + threadIdx.x;
    if (e >= N_EDGES) return;
    float av[8];
    *(float4*)(av+0) = *(const float4*)(eat + (size_t)e*8);
    *(float4*)(av+4) = *(const float4*)(eat + (size_t)e*8 + 4);
    const float is8 = 0.35355339059327373f; // 1/sqrt(8)

    // ---- layer 1: 8 -> 64, silu ----
    float h1[64];
#pragma unroll
    for (int jg = 0; jg < 16; ++jg) {
        float c0=0,c1=0,c2=0,c3=0;
#pragma unroll
        for (int k = 0; k < 8; ++k) {
            float w[4]; *(float4*)w = *(const float4*)(Wfc1 + k*64 + jg*4);
            float hk = av[k];
            c0 += hk*w[0]; c1 += hk*w[1]; c2 += hk*w[2]; c3 += hk*w[3];
        }
        h1[jg*4+0] = silu_f(c0*is8);
        h1[jg*4+1] = silu_f(c1*is8);
        h1[jg*4+2] = silu_f(c2*is8);
        h1[jg*4+3] = silu_f(c3*is8);
    }

    // ---- layer 2: 64 -> 64, silu ----
    float h2[64];
#pragma unroll 1
    for (int jg = 0; jg < 16; ++jg) {
        float c0=0,c1=0,c2=0,c3=0;
#pragma unroll
        for (int k = 0; k < 64; ++k) {
            float w[4]; *(float4*)w = *(const float4*)(Wfc2 + k*64 + jg*4);
            float hk = h1[k];
            c0 += hk*w[0]; c1 += hk*w[1]; c2 += hk*w[2]; c3 += hk*w[3];
        }
        h2[jg*4+0] = silu_f(c0*0.125f);
        h2[jg*4+1] = silu_f(c1*0.125f);
        h2[jg*4+2] = silu_f(c2*0.125f);
        h2[jg*4+3] = silu_f(c3*0.125f);
    }

    // ---- layer 3: 64 -> 224 (75% of FLOPs), fp16 out ----
    __half* wout = WE + (size_t)e*224;
#pragma unroll 1
    for (int jg = 0; jg < 56; ++jg) {
        float c0=0,c1=0,c2=0,c3=0;
#pragma unroll
        for (int k = 0; k < 64; ++k) {
            float w[4]; *(float4*)w = *(const float4*)(Wfc3 + k*224 + jg*4);
            float hk = h2[k];
            c0 += hk*w[0]; c1 += hk*w[1]; c2 += hk*w[2]; c3 += hk*w[3];
        }
        __half2* hp = (__half2*)(wout + jg*4);
        hp[0] = __floats2half2_rn(c0*0.125f, c1*0.125f);
        hp[1] = __floats2half2_rn(c2*0.125f, c3*0.125f);
    }
}

// ---------------------------------------------------------------------------
// K4: wave-per-node gather + tensor product + segment sum (register
// accumulators, NO float atomics) + output GEMMs (k-packed float4 LDS) +
// skip + RMS norms + store.
// ---------------------------------------------------------------------------
__global__ __launch_bounds__(256) void k_aggregate(
    const int* __restrict__ ei, const float* __restrict__ esh,
    const __half* __restrict__ WE, const float* __restrict__ XS,
    const float* __restrict__ SC, const int* __restrict__ CNT,
    const int* __restrict__ LIST,
    const float* __restrict__ W2_0, const float* __restrict__ W2_1,
    const float* __restrict__ g0, const float* __restrict__ g1,
    float* __restrict__ out)
{
    __shared__ float sW0[96*64];   // packed: [(k>>2)*256 + j*4 + (k&3)]
    __shared__ float sW1[128*32];  // packed: [(u>>2)*128 + v*4 + (u&3)]
    __shared__ float aS[4][96];
    __shared__ float aV[4][384];   // [c*128 + row]
    int tid = threadIdx.x;
    for (int t = tid; t < 96*64; t += 256) {
        int k = t >> 6, j = t & 63;
        sW0[(k>>2)*256 + j*4 + (k&3)] = W2_0[t];
    }
    for (int t = tid; t < 128*32; t += 256) {
        int u = t >> 5, v = t & 31;
        sW1[(u>>2)*128 + v*4 + (u&3)] = W2_1[t];
    }
    __syncthreads();

    int lane = tid & 63, wave = tid >> 6;
    int n = blockIdx.x*4 + wave;
    bool act = n < N_NODES;              // wave-uniform
    int u_ = lane & 31;
    bool lo = lane < 32;

    float accM0=0, aV0x=0, aV0y=0, aV0z=0, accM1=0, a12x=0, a12y=0, a12z=0;
    int cnt = 0;
    if (act) { int c = CNT[n]; cnt = c > 64 ? 64 : c; }
    const int* lst = LIST + n*64;
    const int* edst = ei + N_EDGES;      // row 1 = edge_dst

    for (int i = 0; i < cnt; ++i) {
        int e = lst[i];
        int dst = edst[e];
        float4 sh = *(const float4*)(esh + (size_t)e*4); // (sh0, s1x, s1y, s1z)
        const __half* wr = WE + (size_t)e*224;
        const float* xd = XS + (size_t)dst*192;
        float w0 = __half2float(wr[lane]);
        float w1 = __half2float(wr[64 + lane]);
        float sd = xd[lane];
        accM0 += w0*sd*sh.x;                              // m0
        float t1 = w1*sd;                                 // mv0
        aV0x += t1*sh.y; aV0y += t1*sh.z; aV0z += t1*sh.w;
        float4 vv = *(const float4*)(xd + 64 + u_*4);     // vd[u][0..2]
        float wA = __half2float(wr[(lo ? 128 : 192) + u_]); // w2 (lo) / w4 (hi)
        if (lo) {
            float w3v = __half2float(wr[160 + u_]);
            accM1 += w3v*(vv.x*sh.y + vv.y*sh.z + vv.z*sh.w);   // m1 (x INV_SQRT3 later)
            a12x += wA*vv.x*sh.x; a12y += wA*vv.y*sh.x; a12z += wA*vv.z*sh.x; // mv1
        } else {                                           // mv2: w4 * cross(vd, sh1)
            a12x += wA*(vv.y*sh.w - vv.z*sh.z);
            a12y += wA*(vv.z*sh.y - vv.x*sh.w);
            a12z += wA*(vv.x*sh.z - vv.y*sh.y);            // (x INV_SQRT2 later)
        }
    }

    const float SEG = 0.25f;                    // 1/sqrt(16)
    const float IS3 = 0.5773502691896258f;      // 1/sqrt(3)
    const float IS2 = 0.7071067811865476f;      // 1/sqrt(2)
    if (act) {
        aS[wave][lane] = accM0 * SEG;
        aV[wave][0*128 + lane] = aV0x * SEG;
        aV[wave][1*128 + lane] = aV0y * SEG;
        aV[wave][2*128 + lane] = aV0z * SEG;
        if (lo) {
            aS[wave][64 + u_] = accM1 * SEG * IS3;
            aV[wave][0*128 + 64 + u_] = a12x * SEG;
            aV[wave][1*128 + 64 + u_] = a12y * SEG;
            aV[wave][2*128 + 64 + u_] = a12z * SEG;
        } else {
            aV[wave][0*128 + 96 + u_] = a12x * SEG * IS2;
            aV[wave][1*128 + 96 + u_] = a12y * SEG * IS2;
            aV[wave][2*128 + 96 + u_] = a12z * SEG * IS2;
        }
    }
    __syncthreads();
    if (!act) return;

    // out_s = ns @ W2_0 / sqrt(96) + sc_s
    float os = 0;
#pragma unroll 4
    for (int k4 = 0; k4 < 24; ++k4) {
        float a4[4]; *(float4*)a4 = *(const float4*)&aS[wave][k4*4];
        float w4[4]; *(float4*)w4 = *(const float4*)&sW0[k4*256 + lane*4];
        os += a4[0]*w4[0] + a4[1]*w4[1] + a4[2]*w4[2] + a4[3]*w4[3];
    }
    const float IS96 = 0.10206207261596575f;  // 1/sqrt(96)
    os = os*IS96 + SC[(size_t)n*192 + lane];

    // out_v[v][c] = sum_u nv[u][c] * W2_1[u][v] / sqrt(128) + sc_v
    int coff = lo ? 0 : 256;     // c=0 (lo) / c=2 (hi)
    float ov0 = 0, ov1 = 0;
#pragma unroll 4
    for (int u4 = 0; u4 < 32; ++u4) {
        float w4[4]; *(float4*)w4 = *(const float4*)&sW1[u4*128 + u_*4];
        float b0[4]; *(float4*)b0 = *(const float4*)&aV[wave][coff + u4*4];
        float b1[4]; *(float4*)b1 = *(const float4*)&aV[wave][128 + u4*4];  // c=1
        ov0 += b0[0]*w4[0] + b0[1]*w4[1] + b0[2]*w4[2] + b0[3]*w4[3];
        ov1 += b1[0]*w4[0] + b1[1]*w4[1] + b1[2]*w4[2] + b1[3]*w4[3];
    }
    const float IS128 = 0.08838834764831845f; // 1/sqrt(128)
    float4 scv = *(const float4*)(SC + (size_t)n*192 + 64 + u_*4);
    float x0 = ov0*IS128 + (lo ? scv.x : scv.z);
    float x1 = ov1*IS128 + scv.y;   // only meaningful for lo lanes

    // RMS norms (full-wave reductions; act is wave-uniform so all 64 lanes here)
    float r = os*os;
#pragma unroll
    for (int off = 32; off > 0; off >>= 1) r += __shfl_xor(r, off);
    float rms_s = sqrtf(r*(1.0f/64.0f) + EPS_F);
    float rv = lo ? (x0*x0 + x1*x1) : (x0*x0);
#pragma unroll
    for (int off = 32; off > 0; off >>= 1) rv += __shfl_xor(rv, off);
    float rms_v = sqrtf(rv*(1.0f/32.0f) + EPS_F);

    float* orow = out + (size_t)n*160;
    orow[lane] = os / rms_s * g0[lane];
    float gv = g1[u_] / rms_v;
    if (lo) {
        orow[64 + u_*3 + 0] = x0 * gv;
        orow[64 + u_*3 + 1] = x1 * gv;
    } else {
        orow[64 + u_*3 + 2] = x0 * gv;
    }
}

// ---------------------------------------------------------------------------
extern "C" void kernel_launch(void* const* d_in, const int* in_sizes, int n_in,
                              void* d_out, int out_size, void* d_ws, size_t ws_size,
                              hipStream_t stream)
{
    const float* nh   = (const float*)d_in[0];
    const int*   ei   = (const int*)  d_in[1];
    const float* esh  = (const float*)d_in[2];
    const float* eat  = (const float*)d_in[3];
    const float* W1_0 = (const float*)d_in[4];
    const float* W1_1 = (const float*)d_in[5];
    const float* Wfc1 = (const float*)d_in[6];
    const float* Wfc2 = (const float*)d_in[7];
    const float* Wfc3 = (const float*)d_in[8];
    const float* W2_0 = (const float*)d_in[9];
    const float* W2_1 = (const float*)d_in[10];
    const float* Wsc0 = (const float*)d_in[11];
    const float* Wsc1 = (const float*)d_in[12];
    const float* g0   = (const float*)d_in[13];
    const float* g1   = (const float*)d_in[14];
    float* out = (float*)d_out;

    // workspace layout — total ~214 MiB (must stay < 256 MiB)
    char* base = (char*)d_ws;
    float*  XS   = (float*)base;                               // N*192 f32   19.2 MB
    float*  SC   = XS + (size_t)N_NODES*192;                   // N*192 f32   19.2 MB
    __half* WE   = (__half*)(SC + (size_t)N_NODES*192);        // E*224 f16  179.2 MB
    int*    CNT  = (int*)(WE + (size_t)N_EDGES*224);           // N int        0.1 MB
    int*    LIST = CNT + N_NODES;                              // N*64 int     6.4 MB

    hipMemsetAsync(CNT, 0, N_NODES*sizeof(int), stream);
    k_node_pre  <<<(N_NODES+255)/256, 256, 0, stream>>>(nh, W1_0, W1_1, Wsc0, Wsc1, XS, SC);
    k_build_lists<<<(N_EDGES+255)/256, 256, 0, stream>>>(ei, CNT, LIST);
    k_edge_mlp  <<<(N_EDGES+255)/256, 256, 0, stream>>>(eat, Wfc1, Wfc2, Wfc3, WE);
    k_aggregate <<<(N_NODES+3)/4, 256, 0, stream>>>(ei, esh, WE, XS, SC, CNT, LIST,
                                                    W2_0, W2_1, g0, g1, out);
}

// Round 3
// 785.516 us; speedup vs baseline: 1.1132x; 1.1132x over previous
//
#include <hip/hip_runtime.h>
#include <hip/hip_fp16.h>

#define N_NODES 25000
#define N_EDGES 400000
#define EPS_F 1e-5f

__device__ __forceinline__ float silu_f(float x) {
    return x / (1.0f + __expf(-x));
}

// ---------------------------------------------------------------------------
// K1: per-node linear transforms (node-per-lane; weight reads are uniform ->
// scalar loads; node row lives in VGPRs with static indexing only).
// XS/SC row layout (stride 192 f32): [0..63]=s, [64 + v*4 + c]=v (c<3, pad).
// ---------------------------------------------------------------------------
__global__ __launch_bounds__(256) void k_node_pre(
    const float* __restrict__ nh,
    const float* __restrict__ W1_0, const float* __restrict__ W1_1,
    const float* __restrict__ Wsc0, const float* __restrict__ Wsc1,
    float* __restrict__ XS, float* __restrict__ SC)
{
    int n = blockIdx.x * 256 + threadIdx.x;
    if (n >= N_NODES) return;
    const float* row = nh + (size_t)n * 160;
    float* xsrow = XS + (size_t)n * 192;
    float* scrow = SC + (size_t)n * 192;

    // ---- scalar channels ----
    float si[64];
#pragma unroll
    for (int m = 0; m < 16; ++m) {
        float4 t = *(const float4*)(row + m * 4);
        si[4*m+0] = t.x; si[4*m+1] = t.y; si[4*m+2] = t.z; si[4*m+3] = t.w;
    }
#pragma unroll 1
    for (int jg = 0; jg < 16; ++jg) {
        float a0=0,a1=0,a2=0,a3=0,b0=0,b1=0,b2=0,b3=0;
#pragma unroll
        for (int k = 0; k < 64; ++k) {
            float wa[4]; *(float4*)wa = *(const float4*)(W1_0 + k*64 + jg*4);
            float wb[4]; *(float4*)wb = *(const float4*)(Wsc0 + k*64 + jg*4);
            float s = si[k];
            a0 += s*wa[0]; a1 += s*wa[1]; a2 += s*wa[2]; a3 += s*wa[3];
            b0 += s*wb[0]; b1 += s*wb[1]; b2 += s*wb[2]; b3 += s*wb[3];
        }
        const float sc8 = 0.125f; // 1/sqrt(64)
        *(float4*)(xsrow + jg*4) = make_float4(a0*sc8, a1*sc8, a2*sc8, a3*sc8);
        *(float4*)(scrow + jg*4) = make_float4(b0*sc8, b1*sc8, b2*sc8, b3*sc8);
    }

    // ---- vector channels: v_in[u][c] = row[64 + u*3 + c] ----
    float vi[96];
#pragma unroll
    for (int m = 0; m < 24; ++m) {
        float4 t = *(const float4*)(row + 64 + m * 4);
        vi[4*m+0] = t.x; vi[4*m+1] = t.y; vi[4*m+2] = t.z; vi[4*m+3] = t.w;
    }
    const float is32 = 0.17677669529663687f; // 1/sqrt(32)
#pragma unroll 1
    for (int vg = 0; vg < 8; ++vg) {
        float a[4][3], b[4][3];
#pragma unroll
        for (int m = 0; m < 4; ++m) { a[m][0]=a[m][1]=a[m][2]=0.f; b[m][0]=b[m][1]=b[m][2]=0.f; }
#pragma unroll
        for (int u = 0; u < 32; ++u) {
            float wa[4]; *(float4*)wa = *(const float4*)(W1_1 + u*32 + vg*4);
            float wb[4]; *(float4*)wb = *(const float4*)(Wsc1 + u*32 + vg*4);
            float vx = vi[u*3+0], vy = vi[u*3+1], vz = vi[u*3+2];
#pragma unroll
            for (int m = 0; m < 4; ++m) {
                a[m][0] += vx*wa[m]; a[m][1] += vy*wa[m]; a[m][2] += vz*wa[m];
                b[m][0] += vx*wb[m]; b[m][1] += vy*wb[m]; b[m][2] += vz*wb[m];
            }
        }
#pragma unroll
        for (int m = 0; m < 4; ++m) {
            int v = vg*4 + m;
            *(float4*)(xsrow + 64 + v*4) = make_float4(a[m][0]*is32, a[m][1]*is32, a[m][2]*is32, 0.f);
            *(float4*)(scrow + 64 + v*4) = make_float4(b[m][0]*is32, b[m][1]*is32, b[m][2]*is32, 0.f);
        }
    }
}

// ---------------------------------------------------------------------------
// K2: per-src edge lists. Only int atomics (400k). Cap 64 (Poisson(16) max
// over 25k nodes ~34 with overwhelming probability).
// ---------------------------------------------------------------------------
__global__ __launch_bounds__(256) void k_build_lists(
    const int* __restrict__ ei, int* __restrict__ CNT, int* __restrict__ LIST)
{
    int e = blockIdx.x * 256 + threadIdx.x;
    if (e >= N_EDGES) return;
    int src = ei[e];                       // row 0 = edge_src
    int pos = atomicAdd(&CNT[src], 1);
    if (pos < 64) LIST[src*64 + pos] = e;
}

// ---------------------------------------------------------------------------
// K3: FUSED edge MLP, all 3 layers (edge-per-lane). Uniform weight addresses
// -> scalar/broadcast loads (why VALU time ~ fp32 floor). Layer-3 output is
// accumulated 64 B at a time in registers, transposed through a per-wave LDS
// tile, and written as wave-contiguous 1-KB bursts (16 FULL 64-B lines per
// store instruction) — fixes the 5.5x HBM write amplification of per-lane
// strided partial-line stores (R2: WRITE_SIZE 994 MB vs 179 MB ideal).
// ---------------------------------------------------------------------------
__global__ __launch_bounds__(256) void k_edge_mlp(
    const float* __restrict__ eat,
    const float* __restrict__ Wfc1, const float* __restrict__ Wfc2,
    const float* __restrict__ Wfc3,
    __half* __restrict__ WE)
{
    // per-wave staging: 64 edge-rows x 80 B (20 f32; 16B-aligned rows, stride
    // breaks power-of-2 bank aliasing). 20 KB total.
    __shared__ float sbuf[4][64*20];
    int tid  = threadIdx.x;
    int lane = tid & 63, wave = tid >> 6;
    size_t e  = (size_t)blockIdx.x * 256 + tid;
    size_t ec = e < N_EDGES ? e : (size_t)(N_EDGES - 1);  // clamp; no early exit (barriers!)

    float av[8];
    *(float4*)(av+0) = *(const float4*)(eat + ec*8);
    *(float4*)(av+4) = *(const float4*)(eat + ec*8 + 4);
    const float is8 = 0.35355339059327373f; // 1/sqrt(8)

    // ---- layer 1: 8 -> 64, silu ----
    float h1[64];
#pragma unroll
    for (int jg = 0; jg < 16; ++jg) {
        float c0=0,c1=0,c2=0,c3=0;
#pragma unroll
        for (int k = 0; k < 8; ++k) {
            float w[4]; *(float4*)w = *(const float4*)(Wfc1 + k*64 + jg*4);
            float hk = av[k];
            c0 += hk*w[0]; c1 += hk*w[1]; c2 += hk*w[2]; c3 += hk*w[3];
        }
        h1[jg*4+0] = silu_f(c0*is8);
        h1[jg*4+1] = silu_f(c1*is8);
        h1[jg*4+2] = silu_f(c2*is8);
        h1[jg*4+3] = silu_f(c3*is8);
    }

    // ---- layer 2: 64 -> 64, silu ----
    float h2[64];
#pragma unroll 1
    for (int jg = 0; jg < 16; ++jg) {
        float c0=0,c1=0,c2=0,c3=0;
#pragma unroll
        for (int k = 0; k < 64; ++k) {
            float w[4]; *(float4*)w = *(const float4*)(Wfc2 + k*64 + jg*4);
            float hk = h1[k];
            c0 += hk*w[0]; c1 += hk*w[1]; c2 += hk*w[2]; c3 += hk*w[3];
        }
        h2[jg*4+0] = silu_f(c0*0.125f);
        h2[jg*4+1] = silu_f(c1*0.125f);
        h2[jg*4+2] = silu_f(c2*0.125f);
        h2[jg*4+3] = silu_f(c3*0.125f);
    }

    // ---- layer 3: 64 -> 224, fp16 out, 7 chunks of 32 outputs (64 B) ----
    size_t wbase = (size_t)blockIdx.x * 256 + wave*64;  // wave's first edge
    char* WEb = (char*)WE;
#pragma unroll 1
    for (int c = 0; c < 7; ++c) {
        uint2 outp[8];
#pragma unroll
        for (int j = 0; j < 8; ++j) {
            int jg = c*8 + j;
            float c0=0,c1=0,c2=0,c3=0;
#pragma unroll
            for (int k = 0; k < 64; ++k) {
                float w[4]; *(float4*)w = *(const float4*)(Wfc3 + k*224 + jg*4);
                float hk = h2[k];
                c0 += hk*w[0]; c1 += hk*w[1]; c2 += hk*w[2]; c3 += hk*w[3];
            }
            __half2 p0 = __floats2half2_rn(c0*0.125f, c1*0.125f);
            __half2 p1 = __floats2half2_rn(c2*0.125f, c3*0.125f);
            outp[j] = make_uint2(*(unsigned int*)&p0, *(unsigned int*)&p1);
        }
        __syncthreads();   // previous chunk's readers are done
        float* row = &sbuf[wave][lane*20];
        *(uint4*)(row + 0)  = make_uint4(outp[0].x,outp[0].y,outp[1].x,outp[1].y);
        *(uint4*)(row + 4)  = make_uint4(outp[2].x,outp[2].y,outp[3].x,outp[3].y);
        *(uint4*)(row + 8)  = make_uint4(outp[4].x,outp[4].y,outp[5].x,outp[5].y);
        *(uint4*)(row + 12) = make_uint4(outp[6].x,outp[6].y,outp[7].x,outp[7].y);
        __syncthreads();   // tile complete
        int piece = lane & 3;           // 16-B piece within an edge's 64-B chunk
#pragma unroll
        for (int r = 0; r < 4; ++r) {
            int erow = r*16 + (lane >> 2);
            uint4 d = *(uint4*)&sbuf[wave][erow*20 + piece*4];
            size_t eg = wbase + erow;
            if (eg < N_EDGES)
                *(uint4*)(WEb + eg*448 + (size_t)c*64 + piece*16) = d;
        }
    }
}

// ---------------------------------------------------------------------------
// K4: wave-per-node gather + tensor product + segment sum (register
// accumulators, NO float atomics) + output GEMMs (k-packed float4 LDS) +
// skip + RMS norms + store. Edge ids and dst ids are prefetched with one
// coalesced lane-parallel load and distributed via __shfl, removing two
// dependent global loads from every neighbor-loop iteration.
// ---------------------------------------------------------------------------
__global__ __launch_bounds__(256) void k_aggregate(
    const int* __restrict__ ei, const float* __restrict__ esh,
    const __half* __restrict__ WE, const float* __restrict__ XS,
    const float* __restrict__ SC, const int* __restrict__ CNT,
    const int* __restrict__ LIST,
    const float* __restrict__ W2_0, const float* __restrict__ W2_1,
    const float* __restrict__ g0, const float* __restrict__ g1,
    float* __restrict__ out)
{
    __shared__ float sW0[96*64];   // packed: [(k>>2)*256 + j*4 + (k&3)]
    __shared__ float sW1[128*32];  // packed: [(u>>2)*128 + v*4 + (u&3)]
    __shared__ float aS[4][96];
    __shared__ float aV[4][384];   // [c*128 + row]
    int tid = threadIdx.x;
    for (int t = tid; t < 96*64; t += 256) {
        int k = t >> 6, j = t & 63;
        sW0[(k>>2)*256 + j*4 + (k&3)] = W2_0[t];
    }
    for (int t = tid; t < 128*32; t += 256) {
        int u = t >> 5, v = t & 31;
        sW1[(u>>2)*128 + v*4 + (u&3)] = W2_1[t];
    }
    __syncthreads();

    int lane = tid & 63, wave = tid >> 6;
    int n = blockIdx.x*4 + wave;
    bool act = n < N_NODES;              // wave-uniform
    int u_ = lane & 31;
    bool lo = lane < 32;

    float accM0=0, aV0x=0, aV0y=0, aV0z=0, accM1=0, a12x=0, a12y=0, a12z=0;
    int cnt = 0;
    if (act) { int c = CNT[n]; cnt = c > 64 ? 64 : c; }
    const int* edst = ei + N_EDGES;      // row 1 = edge_dst

    // prefetch edge ids + dst ids (coalesced, one load per lane)
    int e_l = 0, dst_l = 0;
    if (act && cnt > 0) {
        int li = lane < cnt ? lane : cnt - 1;
        e_l = LIST[n*64 + li];
        dst_l = edst[e_l];
    }

    for (int i = 0; i < cnt; ++i) {
        int e   = __shfl(e_l, i);
        int dst = __shfl(dst_l, i);
        float4 sh = *(const float4*)(esh + (size_t)e*4); // (sh0, s1x, s1y, s1z)
        const __half* wr = WE + (size_t)e*224;
        const float* xd = XS + (size_t)dst*192;
        float w0 = __half2float(wr[lane]);
        float w1 = __half2float(wr[64 + lane]);
        float sd = xd[lane];
        accM0 += w0*sd*sh.x;                              // m0
        float t1 = w1*sd;                                 // mv0
        aV0x += t1*sh.y; aV0y += t1*sh.z; aV0z += t1*sh.w;
        float4 vv = *(const float4*)(xd + 64 + u_*4);     // vd[u][0..2]
        float wA = __half2float(wr[(lo ? 128 : 192) + u_]); // w2 (lo) / w4 (hi)
        if (lo) {
            float w3v = __half2float(wr[160 + u_]);
            accM1 += w3v*(vv.x*sh.y + vv.y*sh.z + vv.z*sh.w);   // m1 (x INV_SQRT3 later)
            a12x += wA*vv.x*sh.x; a12y += wA*vv.y*sh.x; a12z += wA*vv.z*sh.x; // mv1
        } else {                                           // mv2: w4 * cross(vd, sh1)
            a12x += wA*(vv.y*sh.w - vv.z*sh.z);
            a12y += wA*(vv.z*sh.y - vv.x*sh.w);
            a12z += wA*(vv.x*sh.z - vv.y*sh.y);            // (x INV_SQRT2 later)
        }
    }

    const float SEG = 0.25f;                    // 1/sqrt(16)
    const float IS3 = 0.5773502691896258f;      // 1/sqrt(3)
    const float IS2 = 0.7071067811865476f;      // 1/sqrt(2)
    if (act) {
        aS[wave][lane] = accM0 * SEG;
        aV[wave][0*128 + lane] = aV0x * SEG;
        aV[wave][1*128 + lane] = aV0y * SEG;
        aV[wave][2*128 + lane] = aV0z * SEG;
        if (lo) {
            aS[wave][64 + u_] = accM1 * SEG * IS3;
            aV[wave][0*128 + 64 + u_] = a12x * SEG;
            aV[wave][1*128 + 64 + u_] = a12y * SEG;
            aV[wave][2*128 + 64 + u_] = a12z * SEG;
        } else {
            aV[wave][0*128 + 96 + u_] = a12x * SEG * IS2;
            aV[wave][1*128 + 96 + u_] = a12y * SEG * IS2;
            aV[wave][2*128 + 96 + u_] = a12z * SEG * IS2;
        }
    }
    __syncthreads();
    if (!act) return;

    // out_s = ns @ W2_0 / sqrt(96) + sc_s
    float os = 0;
#pragma unroll 4
    for (int k4 = 0; k4 < 24; ++k4) {
        float a4[4]; *(float4*)a4 = *(const float4*)&aS[wave][k4*4];
        float w4[4]; *(float4*)w4 = *(const float4*)&sW0[k4*256 + lane*4];
        os += a4[0]*w4[0] + a4[1]*w4[1] + a4[2]*w4[2] + a4[3]*w4[3];
    }
    const float IS96 = 0.10206207261596575f;  // 1/sqrt(96)
    os = os*IS96 + SC[(size_t)n*192 + lane];

    // out_v[v][c] = sum_u nv[u][c] * W2_1[u][v] / sqrt(128) + sc_v
    int coff = lo ? 0 : 256;     // c=0 (lo) / c=2 (hi)
    float ov0 = 0, ov1 = 0;
#pragma unroll 4
    for (int u4 = 0; u4 < 32; ++u4) {
        float w4[4]; *(float4*)w4 = *(const float4*)&sW1[u4*128 + u_*4];
        float b0[4]; *(float4*)b0 = *(const float4*)&aV[wave][coff + u4*4];
        float b1[4]; *(float4*)b1 = *(const float4*)&aV[wave][128 + u4*4];  // c=1
        ov0 += b0[0]*w4[0] + b0[1]*w4[1] + b0[2]*w4[2] + b0[3]*w4[3];
        ov1 += b1[0]*w4[0] + b1[1]*w4[1] + b1[2]*w4[2] + b1[3]*w4[3];
    }
    const float IS128 = 0.08838834764831845f; // 1/sqrt(128)
    float4 scv = *(const float4*)(SC + (size_t)n*192 + 64 + u_*4);
    float x0 = ov0*IS128 + (lo ? scv.x : scv.z);
    float x1 = ov1*IS128 + scv.y;   // only meaningful for lo lanes

    // RMS norms (full-wave reductions; act is wave-uniform so all 64 lanes here)
    float r = os*os;
#pragma unroll
    for (int off = 32; off > 0; off >>= 1) r += __shfl_xor(r, off);
    float rms_s = sqrtf(r*(1.0f/64.0f) + EPS_F);
    float rv = lo ? (x0*x0 + x1*x1) : (x0*x0);
#pragma unroll
    for (int off = 32; off > 0; off >>= 1) rv += __shfl_xor(rv, off);
    float rms_v = sqrtf(rv*(1.0f/32.0f) + EPS_F);

    float* orow = out + (size_t)n*160;
    orow[lane] = os / rms_s * g0[lane];
    float gv = g1[u_] / rms_v;
    if (lo) {
        orow[64 + u_*3 + 0] = x0 * gv;
        orow[64 + u_*3 + 1] = x1 * gv;
    } else {
        orow[64 + u_*3 + 2] = x0 * gv;
    }
}

// ---------------------------------------------------------------------------
extern "C" void kernel_launch(void* const* d_in, const int* in_sizes, int n_in,
                              void* d_out, int out_size, void* d_ws, size_t ws_size,
                              hipStream_t stream)
{
    const float* nh   = (const float*)d_in[0];
    const int*   ei   = (const int*)  d_in[1];
    const float* esh  = (const float*)d_in[2];
    const float* eat  = (const float*)d_in[3];
    const float* W1_0 = (const float*)d_in[4];
    const float* W1_1 = (const float*)d_in[5];
    const float* Wfc1 = (const float*)d_in[6];
    const float* Wfc2 = (const float*)d_in[7];
    const float* Wfc3 = (const float*)d_in[8];
    const float* W2_0 = (const float*)d_in[9];
    const float* W2_1 = (const float*)d_in[10];
    const float* Wsc0 = (const float*)d_in[11];
    const float* Wsc1 = (const float*)d_in[12];
    const float* g0   = (const float*)d_in[13];
    const float* g1   = (const float*)d_in[14];
    float* out = (float*)d_out;

    // workspace layout — total ~214 MiB (must stay < 256 MiB)
    char* base = (char*)d_ws;
    float*  XS   = (float*)base;                               // N*192 f32   19.2 MB
    float*  SC   = XS + (size_t)N_NODES*192;                   // N*192 f32   19.2 MB
    __half* WE   = (__half*)(SC + (size_t)N_NODES*192);        // E*224 f16  179.2 MB
    int*    CNT  = (int*)(WE + (size_t)N_EDGES*224);           // N int        0.1 MB
    int*    LIST = CNT + N_NODES;                              // N*64 int     6.4 MB

    hipMemsetAsync(CNT, 0, N_NODES*sizeof(int), stream);
    k_node_pre  <<<(N_NODES+255)/256, 256, 0, stream>>>(nh, W1_0, W1_1, Wsc0, Wsc1, XS, SC);
    k_build_lists<<<(N_EDGES+255)/256, 256, 0, stream>>>(ei, CNT, LIST);
    k_edge_mlp  <<<(N_EDGES+255)/256, 256, 0, stream>>>(eat, Wfc1, Wfc2, Wfc3, WE);
    k_aggregate <<<(N_NODES+3)/4, 256, 0, stream>>>(ei, esh, WE, XS, SC, CNT, LIST,
                                                    W2_0, W2_1, g0, g1, out);
}